// Round 1
// baseline (334.007 us; speedup 1.0000x reference)
//
#include <hip/hip_runtime.h>
#include <stdint.h>

typedef __bf16 bf16x8 __attribute__((ext_vector_type(8)));
typedef float  f32x4  __attribute__((ext_vector_type(4)));

static constexpr int S_DIM = 1024;   // sequence length (= N = K)

// RNE fp32 -> bf16
__device__ __forceinline__ ushort f32_to_bf16_rne(float f) {
    uint32_t u = __builtin_bit_cast(uint32_t, f);
    u += 0x7fffu + ((u >> 16) & 1u);
    return (ushort)(u >> 16);
}
__device__ __forceinline__ uint32_t pk_bf16(float a, float b) {
    return (uint32_t)f32_to_bf16_rne(a) | ((uint32_t)f32_to_bf16_rne(b) << 16);
}
// 8 consecutive-k fp32 -> one MFMA A/B fragment (element e = k-offset e)
__device__ __forceinline__ bf16x8 cvt_frag(f32x4 lo, f32x4 hi) {
    union { uint32_t u[4]; bf16x8 v; } r;
    r.u[0] = pk_bf16(lo[0], lo[1]);
    r.u[1] = pk_bf16(lo[2], lo[3]);
    r.u[2] = pk_bf16(hi[0], hi[1]);
    r.u[3] = pk_bf16(hi[2], hi[3]);
    return r.v;
}

// Wc[kq][j][8] bf16 chunks: chunk (kq, j)[e] = W[kq*8+e][j],
// W[k][j] = (j >= k) ? w[j-k] : 0.  (2 MB, stays L2-resident.)
__global__ void build_wc(const float* __restrict__ w, ushort* __restrict__ Wc) {
    int c  = blockIdx.x * 256 + threadIdx.x;   // kq*1024 + j
    int kq = c >> 10;
    int j  = c & 1023;
    uint32_t p[4];
#pragma unroll
    for (int h = 0; h < 4; ++h) {
        int d0 = j - (kq * 8 + h * 2);
        int d1 = d0 - 1;
        float v0 = (d0 >= 0) ? w[d0] : 0.0f;
        float v1 = (d1 >= 0) ? w[d1] : 0.0f;
        p[h] = (uint32_t)f32_to_bf16_rne(v0) | ((uint32_t)f32_to_bf16_rne(v1) << 16);
    }
    reinterpret_cast<uint4*>(Wc)[c] = make_uint4(p[0], p[1], p[2], p[3]);
}

// Barrier-free row-panel kernel: each block owns 32 rows x ALL 1024 cols.
// NO LDS, NO __syncthreads: each wave loads its own A fragments directly
// from global (all 4 waves hit identical addresses -> L1/L2 broadcast, HBM
// traffic unchanged).  This removes the per-iteration s_waitcnt vmcnt(0)
// barrier drain that serialized the A prefetch + 16 B loads every K-step.
// A is explicitly software-pipelined one iteration ahead; A loads are
// issued BEFORE the B loads so the compiler's counted vmcnt waits for the
// B groups never cover the A prefetch.
// Causal skip per 16-col fragment; cols interleaved across waves (jc = f*4+w)
// so all 4 waves stay balanced at every K-step (waves now run unsynced).
__global__ __launch_bounds__(256, 2) void toep_rowpanel(
    const float* __restrict__ x, const ushort* __restrict__ Wc,
    const float* __restrict__ bias, float* __restrict__ out)
{
    const int tid  = threadIdx.x;
    const int lane = tid & 63;
    const int w    = tid >> 6;        // wave 0..3
    const int l15  = lane & 15;
    const int quad = lane >> 4;
    const int m0   = blockIdx.x * 32;

    // Per-lane A addresses for the 16x16x32 A-fragment:
    //   lane l holds A[row = l15 (+16 for frag1)][k = it*32 + quad*8 + e], e=0..7
    //   = 8 consecutive fp32 = two aligned 16B loads per fragment.
    const float* gxa = x + (size_t)(m0 + l15) * S_DIM + quad * 8;
    const float* gxb = gxa + (size_t)16 * S_DIM;

    // B per-lane base (ushort index): kq = quad, col = w*16 + l15 part
    const ushort* gb = Wc + (size_t)quad * 8192 + w * 128 + l15 * 8;

    f32x4 acc[16][2] = {};   // [frag f][row-frag im], 128 AGPR

    // A stage for it = 0
    f32x4 a0lo = *reinterpret_cast<const f32x4*>(gxa);
    f32x4 a0hi = *reinterpret_cast<const f32x4*>(gxa + 4);
    f32x4 a1lo = *reinterpret_cast<const f32x4*>(gxb);
    f32x4 a1hi = *reinterpret_cast<const f32x4*>(gxb + 4);

    for (int it = 0; it < 32; ++it) {
        // --- issue next-iteration A loads first (plain loads: want L1 reuse
        //     across the 4 waves; clamped tail re-load is harmless) ---
        const int ko = ((it < 31) ? it + 1 : 31) * 32;
        f32x4 n0lo = *reinterpret_cast<const f32x4*>(gxa + ko);
        f32x4 n0hi = *reinterpret_cast<const f32x4*>(gxa + ko + 4);
        f32x4 n1lo = *reinterpret_cast<const f32x4*>(gxb + ko);
        f32x4 n1hi = *reinterpret_cast<const f32x4*>(gxb + ko + 4);

        // causal fragment cutoff for this wave (wave-uniform; waves may
        // diverge from each other freely -- no barriers)
        const int t2   = it * 2;                               // k0 / 16
        const int f_lo = (t2 > w) ? ((t2 - w + 3) >> 2) : 0;   // first live frag
        const bool g0 = f_lo < 4, g1 = f_lo < 8, g2 = f_lo < 12, g3 = f_lo < 16;

        // --- issue ALL live B chunk loads (L2-hot Wc, plain cached loads) ---
        const ushort* gbit = gb + (size_t)it * 32768;
        bf16x8 bf[4][4];
        if (g0) {
#pragma unroll
            for (int i = 0; i < 4; ++i)
                bf[0][i] = *reinterpret_cast<const bf16x8*>(gbit + 0 * 2048 + i * 512);
        }
        if (g1) {
#pragma unroll
            for (int i = 0; i < 4; ++i)
                bf[1][i] = *reinterpret_cast<const bf16x8*>(gbit + 1 * 2048 + i * 512);
        }
        if (g2) {
#pragma unroll
            for (int i = 0; i < 4; ++i)
                bf[2][i] = *reinterpret_cast<const bf16x8*>(gbit + 2 * 2048 + i * 512);
        }
        if (g3) {
#pragma unroll
            for (int i = 0; i < 4; ++i)
                bf[3][i] = *reinterpret_cast<const bf16x8*>(gbit + 3 * 2048 + i * 512);
        }

        // --- convert current A stage (loaded last iteration: latency covered)
        bf16x8 af0 = cvt_frag(a0lo, a0hi);
        bf16x8 af1 = cvt_frag(a1lo, a1hi);

        // --- MFMA groups; compiler emits counted vmcnt per group so group-g
        //     latency hides under group-(g-1) MFMAs ---
        if (g0) {
#pragma unroll
            for (int i = 0; i < 4; ++i) {
                acc[0 + i][0] = __builtin_amdgcn_mfma_f32_16x16x32_bf16(af0, bf[0][i], acc[0 + i][0], 0, 0, 0);
                acc[0 + i][1] = __builtin_amdgcn_mfma_f32_16x16x32_bf16(af1, bf[0][i], acc[0 + i][1], 0, 0, 0);
            }
        }
        if (g1) {
#pragma unroll
            for (int i = 0; i < 4; ++i) {
                acc[4 + i][0] = __builtin_amdgcn_mfma_f32_16x16x32_bf16(af0, bf[1][i], acc[4 + i][0], 0, 0, 0);
                acc[4 + i][1] = __builtin_amdgcn_mfma_f32_16x16x32_bf16(af1, bf[1][i], acc[4 + i][1], 0, 0, 0);
            }
        }
        if (g2) {
#pragma unroll
            for (int i = 0; i < 4; ++i) {
                acc[8 + i][0] = __builtin_amdgcn_mfma_f32_16x16x32_bf16(af0, bf[2][i], acc[8 + i][0], 0, 0, 0);
                acc[8 + i][1] = __builtin_amdgcn_mfma_f32_16x16x32_bf16(af1, bf[2][i], acc[8 + i][1], 0, 0, 0);
            }
        }
        if (g3) {
#pragma unroll
            for (int i = 0; i < 4; ++i) {
                acc[12 + i][0] = __builtin_amdgcn_mfma_f32_16x16x32_bf16(af0, bf[3][i], acc[12 + i][0], 0, 0, 0);
                acc[12 + i][1] = __builtin_amdgcn_mfma_f32_16x16x32_bf16(af1, bf[3][i], acc[12 + i][1], 0, 0, 0);
            }
        }

        // rotate A pipeline
        a0lo = n0lo; a0hi = n0hi; a1lo = n1lo; a1hi = n1hi;
    }

    // epilogue: C/D mapping col = lane&15, row = quad*4 + r (verified m89/m91)
#pragma unroll
    for (int f = 0; f < 16; ++f) {
        const int col = (f * 4 + w) * 16 + l15;
        const float bv = bias[col];
#pragma unroll
        for (int im = 0; im < 2; ++im) {
            const int row0 = m0 + im * 16 + quad * 4;
            float* op = out + (size_t)row0 * S_DIM + col;
#pragma unroll
            for (int r = 0; r < 4; ++r)
                __builtin_nontemporal_store(acc[f][im][r] + bv, op + (size_t)r * S_DIM);
        }
    }
}

extern "C" void kernel_launch(void* const* d_in, const int* in_sizes, int n_in,
                              void* d_out, int out_size, void* d_ws, size_t ws_size,
                              hipStream_t stream) {
    const float* x      = (const float*)d_in[0];   // (32, 1024, 1024) fp32
    const float* weight = (const float*)d_in[1];   // (1, 1024) fp32
    const float* bias   = (const float*)d_in[2];   // (1024,) fp32
    float* out          = (float*)d_out;           // (32, 1024, 1024) fp32

    ushort* Wc = (ushort*)d_ws;                    // 2 MB bf16 Toeplitz, chunked

    build_wc<<<512, 256, 0, stream>>>(weight, Wc);
    toep_rowpanel<<<1024, 256, 0, stream>>>(x, Wc, bias, out);
}

// Round 2
// 299.260 us; speedup vs baseline: 1.1161x; 1.1161x over previous
//
#include <hip/hip_runtime.h>
#include <stdint.h>

typedef __bf16 bf16x8 __attribute__((ext_vector_type(8)));
typedef float  f32x4  __attribute__((ext_vector_type(4)));

static constexpr int S_DIM = 1024;   // sequence length (= N = K)

// RNE fp32 -> bf16
__device__ __forceinline__ ushort f32_to_bf16_rne(float f) {
    uint32_t u = __builtin_bit_cast(uint32_t, f);
    u += 0x7fffu + ((u >> 16) & 1u);
    return (ushort)(u >> 16);
}
__device__ __forceinline__ uint32_t pk_bf16(float a, float b) {
    return (uint32_t)f32_to_bf16_rne(a) | ((uint32_t)f32_to_bf16_rne(b) << 16);
}

// Wc[kq][j][8] bf16 chunks: chunk (kq, j)[e] = W[kq*8+e][j],
// W[k][j] = (j >= k) ? w[j-k] : 0.  (2 MB, stays L2-resident.)
__global__ void build_wc(const float* __restrict__ w, ushort* __restrict__ Wc) {
    int c  = blockIdx.x * 256 + threadIdx.x;   // kq*1024 + j
    int kq = c >> 10;
    int j  = c & 1023;
    uint32_t p[4];
#pragma unroll
    for (int h = 0; h < 4; ++h) {
        int d0 = j - (kq * 8 + h * 2);
        int d1 = d0 - 1;
        float v0 = (d0 >= 0) ? w[d0] : 0.0f;
        float v1 = (d1 >= 0) ? w[d1] : 0.0f;
        p[h] = (uint32_t)f32_to_bf16_rne(v0) | ((uint32_t)f32_to_bf16_rne(v1) << 16);
    }
    reinterpret_cast<uint4*>(Wc)[c] = make_uint4(p[0], p[1], p[2], p[3]);
}

// Row-panel kernel: each block owns 32 rows x ALL 1024 cols.
// x read ONCE (fp32 -> bf16 in-reg -> 2KB LDS dbuf, 1 barrier/iter).
// B frags loaded straight from L2-hot Wc into registers (no LDS).
// ROUND-2 CHANGE (only): __syncthreads() -> s_waitcnt lgkmcnt(0) + raw
// s_barrier + compiler fence.  __syncthreads compiles to a full
// "s_waitcnt vmcnt(0) lgkmcnt(0)" drain, which killed the 2-deep A HBM
// prefetch and exposed the full L2 latency of the 16 B-loads every
// iteration (~2000 stall cycles/iter at 2 waves/SIMD).  The raw-barrier
// idiom waits only for LDS-write visibility; global loads stay in flight
// across the barrier and get counted vmcnt waits at their MFMA uses.
__global__ __launch_bounds__(256, 2) void toep_rowpanel(
    const float* __restrict__ x, const ushort* __restrict__ Wc,
    const float* __restrict__ bias, float* __restrict__ out)
{
    __shared__ __align__(16) ushort As[2][1024];   // [buf][q*256 + m*8 + e], 2 KB each

    const int tid  = threadIdx.x;
    const int lane = tid & 63;
    const int w    = tid >> 6;        // wave 0..3
    const int l15  = lane & 15;
    const int quad = lane >> 4;
    const int m0   = blockIdx.x * 32;

    // A staging: thread covers row sm = tid>>3, k-chunk kc = tid&7 (4 fp32, 16B)
    const int sm = tid >> 3;
    const int kc = tid & 7;
    const float* gx = x + (size_t)(m0 + sm) * S_DIM + kc * 4;
    // LDS write slot (ushort index): q = kc>>1, element base (kc&1)*4
    const int aw = (kc >> 1) * 256 + sm * 8 + (kc & 1) * 4;

    // B per-lane base (ushort index): kq = quad, col = w*16 + l15 part
    const ushort* gb = Wc + (size_t)quad * 8192 + w * 128 + l15 * 8;

    // A-frag read slots (ushort index): chunk (quad, im*16 + l15)
    const int ar0 = quad * 256 + l15 * 8;
    const int ar1 = ar0 + 128;

    f32x4 acc[16][2] = {};   // [frag f][row-frag im], 128 AGPR

    f32x4 av0 = __builtin_nontemporal_load(reinterpret_cast<const f32x4*>(gx));
    f32x4 av1 = __builtin_nontemporal_load(reinterpret_cast<const f32x4*>(gx + 32));

    for (int it = 0; it < 32; ++it) {
        const int p = it & 1;
        // prefetch A two iterations ahead (clamped; redundant at the tail)
        int itn = it + 2; if (itn > 31) itn = 31;
        f32x4 avn = __builtin_nontemporal_load(reinterpret_cast<const f32x4*>(gx + itn * 32));

        // convert current A 16B -> 8B bf16, write LDS
        uint32_t c0 = pk_bf16(av0[0], av0[1]);
        uint32_t c1 = pk_bf16(av0[2], av0[3]);
        *reinterpret_cast<uint2*>(&As[p][aw]) = make_uint2(c0, c1);

        // causal fragment cutoff for this wave (wave-uniform)
        const int t2   = it * 2;                               // k0 / 16
        const int f_lo = (t2 > w) ? ((t2 - w + 3) >> 2) : 0;   // first live frag
        const bool g0 = f_lo < 4, g1 = f_lo < 8, g2 = f_lo < 12, g3 = f_lo < 16;

        // issue ALL live B chunk loads up front (<=16 outstanding b128 from L2;
        // they stay in flight ACROSS the barrier now)
        const ushort* gbit = gb + (size_t)it * 32768;
        bf16x8 bf[4][4];
        if (g0) {
#pragma unroll
            for (int i = 0; i < 4; ++i)
                bf[0][i] = *reinterpret_cast<const bf16x8*>(gbit + 0 * 2048 + i * 512);
        }
        if (g1) {
#pragma unroll
            for (int i = 0; i < 4; ++i)
                bf[1][i] = *reinterpret_cast<const bf16x8*>(gbit + 1 * 2048 + i * 512);
        }
        if (g2) {
#pragma unroll
            for (int i = 0; i < 4; ++i)
                bf[2][i] = *reinterpret_cast<const bf16x8*>(gbit + 2 * 2048 + i * 512);
        }
        if (g3) {
#pragma unroll
            for (int i = 0; i < 4; ++i)
                bf[3][i] = *reinterpret_cast<const bf16x8*>(gbit + 3 * 2048 + i * 512);
        }

        // --- counted-wait barrier (T4): LDS-write visibility only; do NOT
        //     drain vmcnt (A prefetch + B loads remain outstanding) ---
        asm volatile("s_waitcnt lgkmcnt(0)" ::: "memory");
        __builtin_amdgcn_s_barrier();
        asm volatile("" ::: "memory");   // fence: no LDS-read hoist above barrier

        bf16x8 af0 = *reinterpret_cast<const bf16x8*>(&As[p][ar0]);
        bf16x8 af1 = *reinterpret_cast<const bf16x8*>(&As[p][ar1]);

        if (g0) {
#pragma unroll
            for (int i = 0; i < 4; ++i) {
                acc[0 + i][0] = __builtin_amdgcn_mfma_f32_16x16x32_bf16(af0, bf[0][i], acc[0 + i][0], 0, 0, 0);
                acc[0 + i][1] = __builtin_amdgcn_mfma_f32_16x16x32_bf16(af1, bf[0][i], acc[0 + i][1], 0, 0, 0);
            }
        }
        if (g1) {
#pragma unroll
            for (int i = 0; i < 4; ++i) {
                acc[4 + i][0] = __builtin_amdgcn_mfma_f32_16x16x32_bf16(af0, bf[1][i], acc[4 + i][0], 0, 0, 0);
                acc[4 + i][1] = __builtin_amdgcn_mfma_f32_16x16x32_bf16(af1, bf[1][i], acc[4 + i][1], 0, 0, 0);
            }
        }
        if (g2) {
#pragma unroll
            for (int i = 0; i < 4; ++i) {
                acc[8 + i][0] = __builtin_amdgcn_mfma_f32_16x16x32_bf16(af0, bf[2][i], acc[8 + i][0], 0, 0, 0);
                acc[8 + i][1] = __builtin_amdgcn_mfma_f32_16x16x32_bf16(af1, bf[2][i], acc[8 + i][1], 0, 0, 0);
            }
        }
        if (g3) {
#pragma unroll
            for (int i = 0; i < 4; ++i) {
                acc[12 + i][0] = __builtin_amdgcn_mfma_f32_16x16x32_bf16(af0, bf[3][i], acc[12 + i][0], 0, 0, 0);
                acc[12 + i][1] = __builtin_amdgcn_mfma_f32_16x16x32_bf16(af1, bf[3][i], acc[12 + i][1], 0, 0, 0);
            }
        }

        av0 = av1; av1 = avn;
    }

    // epilogue: C/D mapping col = lane&15, row = quad*4 + r (verified m89/m91)
#pragma unroll
    for (int f = 0; f < 16; ++f) {
        const int col = (f * 4 + w) * 16 + l15;
        const float bv = bias[col];
#pragma unroll
        for (int im = 0; im < 2; ++im) {
            const int row0 = m0 + im * 16 + quad * 4;
            float* op = out + (size_t)row0 * S_DIM + col;
#pragma unroll
            for (int r = 0; r < 4; ++r)
                __builtin_nontemporal_store(acc[f][im][r] + bv, op + (size_t)r * S_DIM);
        }
    }
}

extern "C" void kernel_launch(void* const* d_in, const int* in_sizes, int n_in,
                              void* d_out, int out_size, void* d_ws, size_t ws_size,
                              hipStream_t stream) {
    const float* x      = (const float*)d_in[0];   // (32, 1024, 1024) fp32
    const float* weight = (const float*)d_in[1];   // (1, 1024) fp32
    const float* bias   = (const float*)d_in[2];   // (1024,) fp32
    float* out          = (float*)d_out;           // (32, 1024, 1024) fp32

    ushort* Wc = (ushort*)d_ws;                    // 2 MB bf16 Toeplitz, chunked

    build_wc<<<512, 256, 0, stream>>>(weight, Wc);
    toep_rowpanel<<<1024, 256, 0, stream>>>(x, Wc, bias, out);
}

// Round 3
// 271.584 us; speedup vs baseline: 1.2298x; 1.1019x over previous
//
#include <hip/hip_runtime.h>
#include <stdint.h>

typedef __bf16 bf16x8 __attribute__((ext_vector_type(8)));
typedef float  f32x4  __attribute__((ext_vector_type(4)));

static constexpr int S_DIM = 1024;   // sequence length (= N = K)

// RNE fp32 -> bf16
__device__ __forceinline__ ushort f32_to_bf16_rne(float f) {
    uint32_t u = __builtin_bit_cast(uint32_t, f);
    u += 0x7fffu + ((u >> 16) & 1u);
    return (ushort)(u >> 16);
}
__device__ __forceinline__ uint32_t pk_bf16(float a, float b) {
    return (uint32_t)f32_to_bf16_rne(a) | ((uint32_t)f32_to_bf16_rne(b) << 16);
}

// Wc[kq][j][8] bf16 chunks: chunk (kq, j)[e] = W[kq*8+e][j],
// W[k][j] = (j >= k) ? w[j-k] : 0.  (2 MB, stays L2-resident.)
__global__ void build_wc(const float* __restrict__ w, ushort* __restrict__ Wc) {
    int c  = blockIdx.x * 256 + threadIdx.x;   // kq*1024 + j
    int kq = c >> 10;
    int j  = c & 1023;
    uint32_t p[4];
#pragma unroll
    for (int h = 0; h < 4; ++h) {
        int d0 = j - (kq * 8 + h * 2);
        int d1 = d0 - 1;
        float v0 = (d0 >= 0) ? w[d0] : 0.0f;
        float v1 = (d1 >= 0) ? w[d1] : 0.0f;
        p[h] = (uint32_t)f32_to_bf16_rne(v0) | ((uint32_t)f32_to_bf16_rne(v1) << 16);
    }
    reinterpret_cast<uint4*>(Wc)[c] = make_uint4(p[0], p[1], p[2], p[3]);
}

// 64-row panel kernel: each block owns 64 rows x ALL 1024 cols, 8 waves.
// ROUND-3 CHANGE: double the M-tile (32->64 rows/block).  B (Wc) traffic
// through L1/L2 is the critical resource (each block reads the full causal
// k-slice once; rounds 0-2 all pinned at ~128us with identical B traffic).
// 64 rows/block halves aggregate B traffic (1.1 GB -> 0.54 GB) at identical
// per-wave register cost: 8 col-frags x 4 row-frags = 32 MFMA, 128 acc regs.
// Causal gate pi*8+w >= it is a bijection on 0..31 -> per-iter wave
// imbalance <= 1 fragment group.  Wave owns contiguous 32-col pairs so the
// epilogue writes both halves of each 128B line back-to-back (write combine).
// A prefetch issued AFTER B loads: in-order vmcnt means any B wait forces
// older loads complete, so A-last gives the prefetch a full iter of slack.
__global__ __launch_bounds__(512, 2) void toep_rowpanel64(
    const float* __restrict__ x, const ushort* __restrict__ Wc,
    const float* __restrict__ bias, float* __restrict__ out)
{
    __shared__ __align__(16) ushort As[2][2048];   // [buf][q*512 + m*8 + e], 4 KB each

    const int tid  = threadIdx.x;
    const int lane = tid & 63;
    const int w    = tid >> 6;        // wave 0..7
    const int l15  = lane & 15;
    const int quad = lane >> 4;
    const int m0   = blockIdx.x * 64;

    // A staging: thread covers row sm = tid>>3 (0..63), k-chunk kc = tid&7
    const int sm = tid >> 3;
    const int kc = tid & 7;
    const float* gx = x + (size_t)(m0 + sm) * S_DIM + kc * 4;
    // LDS write slot (ushort index): q = kc>>1, element base (kc&1)*4
    const int aw = (kc >> 1) * 512 + sm * 8 + (kc & 1) * 4;

    // B per-lane base (ushort index): kq = quad, col = w*32 + l15 part.
    // Wave w owns col pairs: col = pi*256 + w*32 + h*16 + l15, pi=0..3, h=0..1
    const ushort* gb = Wc + (size_t)quad * 8192 + w * 256 + l15 * 8;

    // A-frag read slot (ushort index): chunk (quad, im*16 + l15)
    const int ar0 = quad * 512 + l15 * 8;

    f32x4 acc[4][2][4] = {};   // [pi][h][im], 128 regs

    f32x4 av0 = __builtin_nontemporal_load(reinterpret_cast<const f32x4*>(gx));
    f32x4 av1 = __builtin_nontemporal_load(reinterpret_cast<const f32x4*>(gx + 32));

    for (int it = 0; it < 32; ++it) {
        const int p = it & 1;

        // convert current A 16B -> 8B bf16, write LDS
        uint32_t c0 = pk_bf16(av0[0], av0[1]);
        uint32_t c1 = pk_bf16(av0[2], av0[3]);
        *reinterpret_cast<uint2*>(&As[p][aw]) = make_uint2(c0, c1);

        // causal gates (wave-uniform): frag pair (pi) live iff pi*8+w >= it
        bool g[4];
#pragma unroll
        for (int pi = 0; pi < 4; ++pi) g[pi] = (pi * 8 + w) >= it;

        // issue live B chunk loads (<=8 b128 from L2-hot Wc)
        const ushort* gbit = gb + (size_t)it * 32768;
        bf16x8 bf[4][2];
        if (g[0]) {
            bf[0][0] = *reinterpret_cast<const bf16x8*>(gbit + 0 * 2048);
            bf[0][1] = *reinterpret_cast<const bf16x8*>(gbit + 0 * 2048 + 128);
        }
        if (g[1]) {
            bf[1][0] = *reinterpret_cast<const bf16x8*>(gbit + 1 * 2048);
            bf[1][1] = *reinterpret_cast<const bf16x8*>(gbit + 1 * 2048 + 128);
        }
        if (g[2]) {
            bf[2][0] = *reinterpret_cast<const bf16x8*>(gbit + 2 * 2048);
            bf[2][1] = *reinterpret_cast<const bf16x8*>(gbit + 2 * 2048 + 128);
        }
        if (g[3]) {
            bf[3][0] = *reinterpret_cast<const bf16x8*>(gbit + 3 * 2048);
            bf[3][1] = *reinterpret_cast<const bf16x8*>(gbit + 3 * 2048 + 128);
        }

        // A prefetch two iterations ahead, issued AFTER the B loads so B
        // vmcnt waits this iter don't force it complete (in-order vmcnt)
        int itn = it + 2; if (itn > 31) itn = 31;
        f32x4 avn = __builtin_nontemporal_load(reinterpret_cast<const f32x4*>(gx + itn * 32));

        // counted-wait barrier: LDS-write visibility only; globals stay in flight
        asm volatile("s_waitcnt lgkmcnt(0)" ::: "memory");
        __builtin_amdgcn_s_barrier();
        asm volatile("" ::: "memory");

        bf16x8 af[4];
#pragma unroll
        for (int im = 0; im < 4; ++im)
            af[im] = *reinterpret_cast<const bf16x8*>(&As[p][ar0 + im * 128]);

        if (g[0]) {
#pragma unroll
            for (int h = 0; h < 2; ++h)
#pragma unroll
                for (int im = 0; im < 4; ++im)
                    acc[0][h][im] = __builtin_amdgcn_mfma_f32_16x16x32_bf16(af[im], bf[0][h], acc[0][h][im], 0, 0, 0);
        }
        if (g[1]) {
#pragma unroll
            for (int h = 0; h < 2; ++h)
#pragma unroll
                for (int im = 0; im < 4; ++im)
                    acc[1][h][im] = __builtin_amdgcn_mfma_f32_16x16x32_bf16(af[im], bf[1][h], acc[1][h][im], 0, 0, 0);
        }
        if (g[2]) {
#pragma unroll
            for (int h = 0; h < 2; ++h)
#pragma unroll
                for (int im = 0; im < 4; ++im)
                    acc[2][h][im] = __builtin_amdgcn_mfma_f32_16x16x32_bf16(af[im], bf[2][h], acc[2][h][im], 0, 0, 0);
        }
        if (g[3]) {
#pragma unroll
            for (int h = 0; h < 2; ++h)
#pragma unroll
                for (int im = 0; im < 4; ++im)
                    acc[3][h][im] = __builtin_amdgcn_mfma_f32_16x16x32_bf16(af[im], bf[3][h], acc[3][h][im], 0, 0, 0);
        }

        av0 = av1; av1 = avn;
    }

    // epilogue: C/D mapping col = lane&15, row = quad*4 + r (verified m89/m91)
    // h=0 / h=1 stores back-to-back -> full 128B line per (pi, im, r) per wave
#pragma unroll
    for (int pi = 0; pi < 4; ++pi) {
        const int colb = pi * 256 + w * 32 + l15;
        const float bv0 = bias[colb];
        const float bv1 = bias[colb + 16];
#pragma unroll
        for (int im = 0; im < 4; ++im) {
            const int row0 = m0 + im * 16 + quad * 4;
            float* op = out + (size_t)row0 * S_DIM + colb;
#pragma unroll
            for (int r = 0; r < 4; ++r) {
                __builtin_nontemporal_store(acc[pi][0][im][r] + bv0, op + (size_t)r * S_DIM);
                __builtin_nontemporal_store(acc[pi][1][im][r] + bv1, op + (size_t)r * S_DIM + 16);
            }
        }
    }
}

extern "C" void kernel_launch(void* const* d_in, const int* in_sizes, int n_in,
                              void* d_out, int out_size, void* d_ws, size_t ws_size,
                              hipStream_t stream) {
    const float* x      = (const float*)d_in[0];   // (32, 1024, 1024) fp32
    const float* weight = (const float*)d_in[1];   // (1, 1024) fp32
    const float* bias   = (const float*)d_in[2];   // (1024,) fp32
    float* out          = (float*)d_out;           // (32, 1024, 1024) fp32

    ushort* Wc = (ushort*)d_ws;                    // 2 MB bf16 Toeplitz, chunked

    build_wc<<<512, 256, 0, stream>>>(weight, Wc);
    toep_rowpanel64<<<512, 512, 0, stream>>>(x, Wc, bias, out);
}

// Round 4
// 263.772 us; speedup vs baseline: 1.2663x; 1.0296x over previous
//
#include <hip/hip_runtime.h>
#include <stdint.h>

typedef __bf16 bf16x8 __attribute__((ext_vector_type(8)));
typedef float  f32x4  __attribute__((ext_vector_type(4)));

static constexpr int S_DIM = 1024;   // sequence length (= N = K)

// RNE fp32 -> bf16
__device__ __forceinline__ ushort f32_to_bf16_rne(float f) {
    uint32_t u = __builtin_bit_cast(uint32_t, f);
    u += 0x7fffu + ((u >> 16) & 1u);
    return (ushort)(u >> 16);
}
__device__ __forceinline__ uint32_t pk_bf16(float a, float b) {
    return (uint32_t)f32_to_bf16_rne(a) | ((uint32_t)f32_to_bf16_rne(b) << 16);
}

// Wc[kq][j][8] bf16 chunks: chunk (kq, j)[e] = W[kq*8+e][j],
// W[k][j] = (j >= k) ? w[j-k] : 0.  (2 MB, stays L2-resident.)
__global__ void build_wc(const float* __restrict__ w, ushort* __restrict__ Wc) {
    int c  = blockIdx.x * 256 + threadIdx.x;   // kq*1024 + j
    int kq = c >> 10;
    int j  = c & 1023;
    uint32_t p[4];
#pragma unroll
    for (int h = 0; h < 4; ++h) {
        int d0 = j - (kq * 8 + h * 2);
        int d1 = d0 - 1;
        float v0 = (d0 >= 0) ? w[d0] : 0.0f;
        float v1 = (d1 >= 0) ? w[d1] : 0.0f;
        p[h] = (uint32_t)f32_to_bf16_rne(v0) | ((uint32_t)f32_to_bf16_rne(v1) << 16);
    }
    reinterpret_cast<uint4*>(Wc)[c] = make_uint4(p[0], p[1], p[2], p[3]);
}

// ROUND-4: phase-structured 64-row panel.  Rounds 0-3 all paid ~3800cy of
// exposed latency per 32-k chunk because a barrier chopped the pipeline
// every chunk (fixed ~77us independent of B traffic).  Now: 256-k PHASES,
// A panel (64 rows x 256 k, bf16) double-buffered in 64KB LDS, ONE barrier
// per phase (5 total vs 33).  The 8 k-chunks inside a phase run with no
// sync, so B-load latency pipelines under MFMA via compiler counted vmcnt.
// A staging is T14-split: issue 8 f32x4 loads at chunk 0 (after chunk-0 B
// loads -> in-order vmcnt drags them only once per phase), convert+ds_write
// at phase end, lgkmcnt-only barrier.  Per-chunk LDS layout / frag maps /
// causal gates / epilogue identical to the verified round-3 kernel.
__global__ __launch_bounds__(512, 2) void toep_phase64(
    const float* __restrict__ x, const ushort* __restrict__ Wc,
    const float* __restrict__ bias, float* __restrict__ out)
{
    __shared__ __align__(16) ushort As[2][8][2048];   // [buf][kk][q*512+m*8+e], 64 KB

    const int tid  = threadIdx.x;
    const int lane = tid & 63;
    const int w    = tid >> 6;        // wave 0..7
    const int l15  = lane & 15;
    const int quad = lane >> 4;
    const int m0   = blockIdx.x * 64;

    // A staging: thread covers row sm = tid>>3 (0..63), k-slot kc = tid&7
    const int sm = tid >> 3;
    const int kc = tid & 7;
    const float* gx = x + (size_t)(m0 + sm) * S_DIM + kc * 4;
    const int aw = (kc >> 1) * 512 + sm * 8 + (kc & 1) * 4;   // within As[buf][kk]

    // B per-lane base (ushort index): kq = quad, col = w*32 + l15 part
    const ushort* gb = Wc + (size_t)quad * 8192 + w * 256 + l15 * 8;

    // A-frag read slot (ushort index) within As[buf][kk]
    const int ar0 = quad * 512 + l15 * 8;

    f32x4 acc[4][2][4] = {};   // [pi][h][im], 128 acc regs

    // ---- prologue: stage phase 0 into buf 0 ----
    {
        f32x4 v0[8];
#pragma unroll
        for (int kk = 0; kk < 8; ++kk)
            v0[kk] = __builtin_nontemporal_load(reinterpret_cast<const f32x4*>(gx + kk * 32));
#pragma unroll
        for (int kk = 0; kk < 8; ++kk)
            *reinterpret_cast<uint2*>(&As[0][kk][aw]) =
                make_uint2(pk_bf16(v0[kk][0], v0[kk][1]), pk_bf16(v0[kk][2], v0[kk][3]));
    }
    __syncthreads();   // prologue: full sync is fine (nothing useful in flight)

    for (int p = 0; p < 4; ++p) {
        const int b = p & 1;
        f32x4 v[8];   // next-phase A stage (live across the phase; watch VGPR)

#pragma unroll
        for (int kk = 0; kk < 8; ++kk) {
            const int it = p * 8 + kk;
            // causal gates (wave-uniform): pi group live iff pi*8+w >= it.
            // g3 dies last: !g3 => whole chunk dead for this wave.
            const bool g0 = (w      ) >= it;
            const bool g1 = (w +  8 ) >= it;
            const bool g2 = (w + 16 ) >= it;
            const bool g3 = (w + 24 ) >= it;
            if (!g3) continue;   // never skips kk==0 while staging (p<3 => it<=16<24+w)

            // B loads for this chunk (L2-hot Wc)
            const ushort* gbit = gb + (size_t)it * 32768;
            bf16x8 bf[4][2];
            if (g0) {
                bf[0][0] = *reinterpret_cast<const bf16x8*>(gbit);
                bf[0][1] = *reinterpret_cast<const bf16x8*>(gbit + 128);
            }
            if (g1) {
                bf[1][0] = *reinterpret_cast<const bf16x8*>(gbit + 2048);
                bf[1][1] = *reinterpret_cast<const bf16x8*>(gbit + 2048 + 128);
            }
            if (g2) {
                bf[2][0] = *reinterpret_cast<const bf16x8*>(gbit + 4096);
                bf[2][1] = *reinterpret_cast<const bf16x8*>(gbit + 4096 + 128);
            }
            if (g3) {
                bf[3][0] = *reinterpret_cast<const bf16x8*>(gbit + 6144);
                bf[3][1] = *reinterpret_cast<const bf16x8*>(gbit + 6144 + 128);
            }

            // T14 issue-early: next-phase A loads, once per phase, after the
            // chunk-0 B loads (so only chunk-1's B wait drags them)
            if (kk == 0 && p < 3) {
                const float* gxn = gx + (p + 1) * 256;
#pragma unroll
                for (int j = 0; j < 8; ++j)
                    v[j] = __builtin_nontemporal_load(reinterpret_cast<const f32x4*>(gxn + j * 32));
            }

            // A fragments from LDS (2-way bank aliasing only -> free)
            bf16x8 af[4];
#pragma unroll
            for (int im = 0; im < 4; ++im)
                af[im] = *reinterpret_cast<const bf16x8*>(&As[b][kk][ar0 + im * 128]);

            if (g0) {
#pragma unroll
                for (int h = 0; h < 2; ++h)
#pragma unroll
                    for (int im = 0; im < 4; ++im)
                        acc[0][h][im] = __builtin_amdgcn_mfma_f32_16x16x32_bf16(af[im], bf[0][h], acc[0][h][im], 0, 0, 0);
            }
            if (g1) {
#pragma unroll
                for (int h = 0; h < 2; ++h)
#pragma unroll
                    for (int im = 0; im < 4; ++im)
                        acc[1][h][im] = __builtin_amdgcn_mfma_f32_16x16x32_bf16(af[im], bf[1][h], acc[1][h][im], 0, 0, 0);
            }
            if (g2) {
#pragma unroll
                for (int h = 0; h < 2; ++h)
#pragma unroll
                    for (int im = 0; im < 4; ++im)
                        acc[2][h][im] = __builtin_amdgcn_mfma_f32_16x16x32_bf16(af[im], bf[2][h], acc[2][h][im], 0, 0, 0);
            }
            if (g3) {
#pragma unroll
                for (int h = 0; h < 2; ++h)
#pragma unroll
                    for (int im = 0; im < 4; ++im)
                        acc[3][h][im] = __builtin_amdgcn_mfma_f32_16x16x32_bf16(af[im], bf[3][h], acc[3][h][im], 0, 0, 0);
            }
        }

        // T14 write-late: convert + stage next phase into the other buffer,
        // then LDS-visibility-only barrier (globals stay in flight)
        if (p < 3) {
#pragma unroll
            for (int kk = 0; kk < 8; ++kk)
                *reinterpret_cast<uint2*>(&As[b ^ 1][kk][aw]) =
                    make_uint2(pk_bf16(v[kk][0], v[kk][1]), pk_bf16(v[kk][2], v[kk][3]));
            asm volatile("s_waitcnt lgkmcnt(0)" ::: "memory");
            __builtin_amdgcn_s_barrier();
            asm volatile("" ::: "memory");
        }
    }

    // epilogue: C/D mapping col = lane&15, row = quad*4 + r (verified m89/m91)
#pragma unroll
    for (int pi = 0; pi < 4; ++pi) {
        const int colb = pi * 256 + w * 32 + l15;
        const float bv0 = bias[colb];
        const float bv1 = bias[colb + 16];
#pragma unroll
        for (int im = 0; im < 4; ++im) {
            const int row0 = m0 + im * 16 + quad * 4;
            float* op = out + (size_t)row0 * S_DIM + colb;
#pragma unroll
            for (int r = 0; r < 4; ++r) {
                __builtin_nontemporal_store(acc[pi][0][im][r] + bv0, op + (size_t)r * S_DIM);
                __builtin_nontemporal_store(acc[pi][1][im][r] + bv1, op + (size_t)r * S_DIM + 16);
            }
        }
    }
}

extern "C" void kernel_launch(void* const* d_in, const int* in_sizes, int n_in,
                              void* d_out, int out_size, void* d_ws, size_t ws_size,
                              hipStream_t stream) {
    const float* x      = (const float*)d_in[0];   // (32, 1024, 1024) fp32
    const float* weight = (const float*)d_in[1];   // (1, 1024) fp32
    const float* bias   = (const float*)d_in[2];   // (1024,) fp32
    float* out          = (float*)d_out;           // (32, 1024, 1024) fp32

    ushort* Wc = (ushort*)d_ws;                    // 2 MB bf16 Toeplitz, chunked

    build_wc<<<512, 256, 0, stream>>>(weight, Wc);
    toep_phase64<<<512, 512, 0, stream>>>(x, Wc, bias, out);
}